// Round 11
// baseline (243.999 us; speedup 1.0000x reference)
//
#include <hip/hip_runtime.h>
#include <cstdint>

#define HW  128
#define NCH 256
#define NOC 18      // G*K*K
#define PLANE (HW * HW)
#define EPSBN 1e-5f

typedef __attribute__((ext_vector_type(8)))  short bf16x8;
typedef __attribute__((ext_vector_type(16))) float f32x16;

__device__ __forceinline__ unsigned short f2bf(float f) {
    union { float f; uint32_t u; } c; c.f = f;
    uint32_t u = c.u;
    uint32_t r = u + 0x7FFFu + ((u >> 16) & 1u);   // RNE
    return (unsigned short)(r >> 16);
}

__device__ __forceinline__ float f4c(const float4& f, int c) {
    return c == 0 ? f.x : c == 1 ? f.y : c == 2 ? f.z : f.w;  // c is compile-time
}

// LDS tile [slot(4)][px(130)][ic(64)] bf16, px stride 128 B.
// XOR (px>>2)&7 into the 16B-granule bits: spreads both the px4-strided
// writes and the px-consecutive b128 reads over the banks (~4-way floor).
__device__ __forceinline__ int lds_off(int slot, int px, int ic) {
    int b = ((slot * 130 + px) * 64 + ic) * 2;
    return b ^ (((px >> 2) & 7) << 4);
}

// ------------- Kernel W: pack weights -> wB[tap][ic>>3][oc(32 pad)][ic&7] bf16
__global__ __launch_bounds__(256) void pasa_wprep(
    const float* __restrict__ w, unsigned short* __restrict__ wB)
{
    int idx = blockIdx.x * 256 + threadIdx.x;      // 9*32*32*8 = 73728
    int icl = idx & 7;
    int oc  = (idx >> 3) & 31;
    int icb = (idx >> 8) & 31;
    int tap = idx >> 13;
    int ic  = icb * 8 + icl;
    float v = (oc < NOC) ? w[((size_t)oc * NCH + ic) * 9 + tap] : 0.0f;
    wB[idx] = f2bf(v);
}

// ------------- Kernel A: implicit-GEMM conv + BN + softmax (fused) ---------
// R5 structure; staging vectorized: 16 x float4 px-contiguous loads/thread
// + in-register transpose -> swizzled LDS [px][ic] bf16 writes.
__global__ __launch_bounds__(512, 4) void pasa_conv_mfma(
    const float* __restrict__ x, const unsigned short* __restrict__ wB,
    const float* __restrict__ gamma, const float* __restrict__ beta,
    const float* __restrict__ rmean, const float* __restrict__ rvar,
    float* __restrict__ sigma)
{
    __shared__ __align__(16) char lds[4 * 130 * 64 * 2];   // 66560 B

    int flat = blockIdx.x;                 // [0,512)
    int nf   = (flat & 7) * 64 + (flat >> 3);  // XCD gets one image
    const int n  = nf >> 6;
    const int y0 = (nf & 63) * 2;

    const int tid  = threadIdx.x;
    const int lane = tid & 63;
    const int wv   = tid >> 6;             // wave 0..7
    const int m    = lane & 31;            // MFMA col (pixel in tile)
    const int hi   = lane >> 5;            // k-half selector

    const int team = tid >> 7;             // 0..3 -> LDS row slot
    const int t    = tid & 127;            // thread in team
    const int px4  = t & 31;               // float4 slot: gpx 4*px4..+3
    const int icg  = t >> 5;               // 16-ic group 0..3

    int grow;                              // staged row (reflect)
    if      (team == 0) grow = (y0 == 0) ? 1 : y0 - 1;
    else if (team == 1) grow = y0;
    else if (team == 2) grow = y0 + 1;
    else                grow = (y0 + 1 == HW - 1) ? HW - 2 : y0 + 2;

    const float* xrow = x + (size_t)n * NCH * PLANE + (size_t)grow * HW;

    const int out_row = wv >> 2;
    const int px_tile = (wv & 3) * 32;

    f32x16 acc;
    #pragma unroll
    for (int i = 0; i < 16; ++i) acc[i] = 0.0f;

    for (int chunk = 0; chunk < 4; ++chunk) {
        const int icb = chunk * 64;
        // halo columns: slot0 <- gpx1 (reflect -1), slot129 <- gpx126
        const int hic   = t & 63;
        const int hpx   = (t < 64) ? 1 : 126;
        const int hslot = (t < 64) ? 0 : 129;
        float hv = xrow[(size_t)(icb + hic) * PLANE + hpx];

        // main: 16 px-contiguous float4 loads (4x wider, 16-deep MLP)
        float4 v0[8], v1[8];
        #pragma unroll
        for (int j = 0; j < 8; ++j)
            v0[j] = *(const float4*)(xrow + (size_t)(icb + icg * 16 + j) * PLANE + px4 * 4);
        #pragma unroll
        for (int j = 0; j < 8; ++j)
            v1[j] = *(const float4*)(xrow + (size_t)(icb + icg * 16 + 8 + j) * PLANE + px4 * 4);

        *(unsigned short*)(lds + lds_off(team, hslot, hic)) = f2bf(hv);

        // in-register transpose: component c -> px slot 4*px4+c+1
        #pragma unroll
        for (int c = 0; c < 4; ++c) {
            int4 d;
            d.x = (uint32_t)f2bf(f4c(v0[0], c)) | ((uint32_t)f2bf(f4c(v0[1], c)) << 16);
            d.y = (uint32_t)f2bf(f4c(v0[2], c)) | ((uint32_t)f2bf(f4c(v0[3], c)) << 16);
            d.z = (uint32_t)f2bf(f4c(v0[4], c)) | ((uint32_t)f2bf(f4c(v0[5], c)) << 16);
            d.w = (uint32_t)f2bf(f4c(v0[6], c)) | ((uint32_t)f2bf(f4c(v0[7], c)) << 16);
            *(int4*)(lds + lds_off(team, px4 * 4 + c + 1, icg * 16)) = d;
            int4 e;
            e.x = (uint32_t)f2bf(f4c(v1[0], c)) | ((uint32_t)f2bf(f4c(v1[1], c)) << 16);
            e.y = (uint32_t)f2bf(f4c(v1[2], c)) | ((uint32_t)f2bf(f4c(v1[3], c)) << 16);
            e.z = (uint32_t)f2bf(f4c(v1[4], c)) | ((uint32_t)f2bf(f4c(v1[5], c)) << 16);
            e.w = (uint32_t)f2bf(f4c(v1[6], c)) | ((uint32_t)f2bf(f4c(v1[7], c)) << 16);
            *(int4*)(lds + lds_off(team, px4 * 4 + c + 1, icg * 16 + 8)) = e;
        }
        __syncthreads();
        // ---- MFMA: 9 taps x 4 k-steps, D = W·X ----
        #pragma unroll
        for (int tap = 0; tap < 9; ++tap) {
            const int dy = tap / 3;
            const int dx = tap % 3 - 1;
            const int slot = out_row + dy;
            const int apx  = px_tile + m + 1 + dx;
            #pragma unroll
            for (int ks = 0; ks < 4; ++ks) {
                const int k0 = ks * 16;
                bf16x8 a = *(const bf16x8*)(lds + lds_off(slot, apx, k0 + hi * 8));
                bf16x8 b = *(const bf16x8*)(wB +
                    (((size_t)tap * 32 + ((icb + k0) >> 3) + hi) * 32 + m) * 8);
                acc = __builtin_amdgcn_mfma_f32_32x32x16_bf16(b, a, acc, 0, 0, 0);
            }
        }
        __syncthreads();
    }

    // C/D layout: col(px)=lane&31, row(oc)=(r&3)+8*(r>>2)+4*hi
    float vals[16];
    float mx = -3.0e38f;
    #pragma unroll
    for (int r = 0; r < 16; ++r) {
        int oc = (r & 3) + 8 * (r >> 2) + 4 * hi;
        float v = -3.0e38f;
        if (oc < NOC) {
            float sc = gamma[oc] * rsqrtf(rvar[oc] + EPSBN);
            float b  = beta[oc] - rmean[oc] * sc;
            v = fmaf(acc[r], sc, b);
        }
        vals[r] = v;
        mx = fmaxf(mx, v);
    }
    mx = fmaxf(mx, __shfl_xor(mx, 32));
    float s = 0.0f;
    #pragma unroll
    for (int r = 0; r < 16; ++r) {
        int oc = (r & 3) + 8 * (r >> 2) + 4 * hi;
        float e = (oc < NOC) ? __expf(vals[r] - mx) : 0.0f;
        vals[r] = e;
        s += e;
    }
    s += __shfl_xor(s, 32);
    const float inv = 1.0f / s;

    float* so = sigma + (size_t)n * NOC * PLANE
              + (size_t)(y0 + out_row) * HW + px_tile + m;
    #pragma unroll
    for (int r = 0; r < 16; ++r) {
        int oc = (r & 3) + 8 * (r >> 2) + 4 * hi;
        if (oc < NOC) so[(size_t)oc * PLANE] = vals[r] * inv;
    }
}

// ------------- Kernel B: pooling with explicit 2-deep channel pipeline -----
struct Ld9 {
    float a0, a1, b0, b1, c0, c1;
    float4 ma, mb, mc;
};

__global__ __launch_bounds__(256, 4) void pasa_pool(
    const float* __restrict__ x, const float* __restrict__ sigma,
    float* __restrict__ out)
{
    int flat = blockIdx.x;                 // [0,2048)
    int nf   = (flat & 7) * 256 + (flat >> 3);   // XCD owns one image
    const int n       = nf >> 8;
    const int chsplit = (nf >> 5) & 7;
    const int yq      = nf & 31;

    const int q = threadIdx.x & 31;
    const int r = (threadIdx.x >> 5) & 3;
    const int s = threadIdx.x >> 7;        // group 0/1

    const int y   = yq * 4 + r;
    const int px0 = q * 4;

    const int ym = (y == 0)      ? 1      : y - 1;
    const int yp = (y == HW - 1) ? HW - 2 : y + 1;
    const int lx = (px0 == 0)        ? 1      : px0 - 1;
    const int rx = (px0 + 4 > HW - 1)? HW - 2 : px0 + 4;

    const size_t ymO = (size_t)ym * HW;
    const size_t yO  = (size_t)y  * HW;
    const size_t ypO = (size_t)yp * HW;

    const float* sg = sigma + ((size_t)n * NOC + s * 9) * PLANE
                            + (size_t)y * HW + px0;
    float sgv[9][4];
    #pragma unroll
    for (int k = 0; k < 9; ++k) {
        float4 tt = *(const float4*)(sg + (size_t)k * PLANE);
        sgv[k][0] = tt.x; sgv[k][1] = tt.y; sgv[k][2] = tt.z; sgv[k][3] = tt.w;
    }

    const int c0 = s * 128 + chsplit * 16;
    const float* xn = x + (size_t)n * NCH * PLANE;
    float*       on = out + (size_t)n * NCH * PLANE;

#define LOAD9(ch, L) do {                                               \
        const float* xcp = xn + (size_t)(ch) * PLANE;                   \
        (L).a0 = xcp[ymO + lx];                                         \
        (L).ma = *(const float4*)(xcp + ymO + px0);                     \
        (L).a1 = xcp[ymO + rx];                                         \
        (L).b0 = xcp[yO + lx];                                          \
        (L).mb = *(const float4*)(xcp + yO + px0);                      \
        (L).b1 = xcp[yO + rx];                                          \
        (L).c0 = xcp[ypO + lx];                                         \
        (L).mc = *(const float4*)(xcp + ypO + px0);                     \
        (L).c1 = xcp[ypO + rx];                                         \
    } while (0)

#define FMASTORE(ch, L) do {                                            \
        float ov[4] = {0.f, 0.f, 0.f, 0.f};                             \
        {                                                               \
            float wv[6] = {(L).a0, (L).ma.x, (L).ma.y, (L).ma.z, (L).ma.w, (L).a1}; \
            _Pragma("unroll") for (int j = 0; j < 4; ++j)               \
                _Pragma("unroll") for (int dx = 0; dx < 3; ++dx)        \
                    ov[j] = fmaf(wv[j + dx], sgv[dx][j], ov[j]);        \
        }                                                               \
        {                                                               \
            float wv[6] = {(L).b0, (L).mb.x, (L).mb.y, (L).mb.z, (L).mb.w, (L).b1}; \
            _Pragma("unroll") for (int j = 0; j < 4; ++j)               \
                _Pragma("unroll") for (int dx = 0; dx < 3; ++dx)        \
                    ov[j] = fmaf(wv[j + dx], sgv[3 + dx][j], ov[j]);    \
        }                                                               \
        {                                                               \
            float wv[6] = {(L).c0, (L).mc.x, (L).mc.y, (L).mc.z, (L).mc.w, (L).c1}; \
            _Pragma("unroll") for (int j = 0; j < 4; ++j)               \
                _Pragma("unroll") for (int dx = 0; dx < 3; ++dx)        \
                    ov[j] = fmaf(wv[j + dx], sgv[6 + dx][j], ov[j]);    \
        }                                                               \
        float4 o4 = { ov[0], ov[1], ov[2], ov[3] };                     \
        *(float4*)(on + (size_t)(ch) * PLANE + yO + px0) = o4;          \
    } while (0)

    Ld9 A, B;
    LOAD9(c0, A);
    #pragma unroll
    for (int cc = 0; cc < 16; cc += 2) {
        LOAD9(c0 + cc + 1, B);
        FMASTORE(c0 + cc, A);
        if (cc + 2 < 16) LOAD9(c0 + cc + 2, A);
        FMASTORE(c0 + cc + 1, B);
    }
#undef LOAD9
#undef FMASTORE
}

extern "C" void kernel_launch(void* const* d_in, const int* in_sizes, int n_in,
                              void* d_out, int out_size, void* d_ws, size_t ws_size,
                              hipStream_t stream) {
    const float* x     = (const float*)d_in[0];
    const float* w     = (const float*)d_in[1];
    const float* gamma = (const float*)d_in[2];
    const float* beta  = (const float*)d_in[3];
    const float* rmean = (const float*)d_in[4];
    const float* rvar  = (const float*)d_in[5];
    float* out   = (float*)d_out;
    float* sigma = (float*)d_ws;                 // 8*18*16384*4 = 9.44 MB

    // wB scratch in d_out (pool fully overwrites d_out afterwards)
    unsigned short* wB = (unsigned short*)(out + (size_t)16 * 1024 * 1024);

    pasa_wprep<<<dim3(288), dim3(256), 0, stream>>>(w, wB);
    pasa_conv_mfma<<<dim3(512), dim3(512), 0, stream>>>(
        x, wB, gamma, beta, rmean, rvar, sigma);
    pasa_pool<<<dim3(2048), dim3(256), 0, stream>>>(x, sigma, out);
}